// Round 3
// baseline (4112.390 us; speedup 1.0000x reference)
//
#include <hip/hip_runtime.h>
#include <cstddef>
#include <cstdint>

#define H 1280
#define RB 8
#define BS 160
#define HEADS 20
#define HD 64
#define BATCH 16
#define SEQ 1024
#define SE 77
#define CENC 768
#define CONSTR 1.28f
#define EPS_N 1e-8f

// workspace offsets (in floats)
#define QS_OFF    0u           // 614400
#define PA_OFF    614400u
#define PB_OFF    1228800u
#define WQF_OFF   1843200u     // 1638400
#define WKF_OFF   3481600u     // 983040
#define WVF_OFF   4464640u     // 983040
#define QBUF_OFF  5447680u     // 20971520
#define KBUF_OFF  26419200u    // 1576960
#define VBUF_OFF  27996160u    // 1576960
#define HIDH_OFF  29573120u    // 10485760 floats (20971520 shorts)
#define HIDL_OFF  40058880u    // 10485760
#define ENCH_OFF  50544640u    // 473088
#define ENCL_OFF  51017728u    // 473088
#define WQTH_OFF  51490816u    // 819200
#define WQTL_OFF  52310016u    // 819200
#define WKTH_OFF  53129216u    // 491520
#define WKTL_OFF  53620736u    // 491520
#define WVTH_OFF  54112256u    // 491520
#define WVTL_OFF  54603776u    // 491520
#define WOTH_OFF  55095296u    // 819200
#define WOTL_OFF  55914496u    // 819200
// AO (attn output, bf16 hi/lo) overlays HIDH/HIDL (dead after q GEMM)
// norms (3 floats) overlays PA (dead until first horner)

typedef __attribute__((ext_vector_type(8))) short short8v;
typedef __attribute__((ext_vector_type(4))) float f32x4;

__device__ __forceinline__ short f2bf(float x) {
  unsigned u = __float_as_uint(x);
  unsigned r = (u + 0x7fffu + ((u >> 16) & 1u)) >> 16;
  return (short)r;
}
__device__ __forceinline__ float bf2f(short h) {
  return __uint_as_float(((unsigned)(unsigned short)h) << 16);
}

// ---------------------------------------------------------------------------
// 1a) zero the 3-float norm accumulator
// ---------------------------------------------------------------------------
__global__ void zero_norms(float* __restrict__ norms) {
  if (threadIdx.x < 3) norms[threadIdx.x] = 0.f;
}

// 1b) partial Frobenius norms of Q = W - W^T. grid = 24 (w*8+r), 256 thr.
__global__ __launch_bounds__(256) void skew_norm_kernel(
    const float* __restrict__ W0, const float* __restrict__ W1,
    const float* __restrict__ W2, float* __restrict__ norms) {
  int wr = blockIdx.x;
  int w = wr >> 3, r = wr & 7;
  const float* Wb =
      ((w == 0) ? W0 : ((w == 1) ? W1 : W2)) + (size_t)r * BS * BS;
  float local = 0.f;
  for (int idx = threadIdx.x; idx < BS * BS; idx += 256) {
    int i = idx / BS, j = idx % BS;
    float q = Wb[idx] - Wb[j * BS + i];
    local += q * q;
  }
#pragma unroll
  for (int off = 32; off > 0; off >>= 1) local += __shfl_down(local, off);
  __shared__ float wsum[4];
  if ((threadIdx.x & 63) == 0) wsum[threadIdx.x >> 6] = local;
  __syncthreads();
  if (threadIdx.x == 0)
    atomicAdd(&norms[w], wsum[0] + wsum[1] + wsum[2] + wsum[3]);
}

// 1c) scale pass: Qs = (W - W^T) * (min(n,c)+eps)/(n+eps). grid 2400, 256 thr.
__global__ __launch_bounds__(256) void skew_scale_kernel(
    const float* __restrict__ W0, const float* __restrict__ W1,
    const float* __restrict__ W2, const float* __restrict__ norms,
    float* __restrict__ Qs) {
  int idx = blockIdx.x * 256 + threadIdx.x;  // < 614400
  int w = idx / (RB * BS * BS);
  int rem = idx - w * (RB * BS * BS);
  int r = rem / (BS * BS);
  int ij = rem - r * (BS * BS);
  int i = ij / BS, j = ij - i * BS;
  const float* Wb =
      ((w == 0) ? W0 : ((w == 1) ? W1 : W2)) + (size_t)r * BS * BS;
  float n = sqrtf(norms[w]);
  float sc = (fminf(n, CONSTR) + EPS_N) / (n + EPS_N);
  Qs[idx] = (Wb[ij] - Wb[j * BS + i]) * sc;
}

// ---------------------------------------------------------------------------
// 2) Horner step: Pout = Q @ (Pin + I) per 160x160 block.
// ---------------------------------------------------------------------------
__global__ __launch_bounds__(256) void horner_kernel(
    const float* __restrict__ Qs, const float* __restrict__ Pin,
    float* __restrict__ Pout) {
  int wr = blockIdx.x / 25;
  int st = blockIdx.x % 25;
  int is = st / 5, js = st % 5;
  const float* Ag = Qs + (size_t)wr * BS * BS;
  const float* Bg = Pin + (size_t)wr * BS * BS;
  float* Og = Pout + (size_t)wr * BS * BS;
  __shared__ float As[32 * 160];
  __shared__ float Bsh[160 * 32];
  for (int idx = threadIdx.x; idx < 32 * 160; idx += 256) {
    int rr = idx / 160, c = idx % 160;
    As[idx] = Ag[(is * 32 + rr) * 160 + c];
    int k = idx / 32, jj = idx % 32;
    int jglob = js * 32 + jj;
    float v = Bg[k * 160 + jglob];
    if (k == jglob) v += 1.f;
    Bsh[k * 32 + jj] = v;
  }
  __syncthreads();
  int ti = threadIdx.x / 32, tj = threadIdx.x % 32;
  float a0 = 0.f, a1 = 0.f, a2 = 0.f, a3 = 0.f;
  for (int k = 0; k < 160; ++k) {
    float b = Bsh[k * 32 + tj];
    a0 += As[(ti)*160 + k] * b;
    a1 += As[(ti + 8) * 160 + k] * b;
    a2 += As[(ti + 16) * 160 + k] * b;
    a3 += As[(ti + 24) * 160 + k] * b;
  }
  Og[(is * 32 + ti) * 160 + js * 32 + tj] = a0;
  Og[(is * 32 + ti + 8) * 160 + js * 32 + tj] = a1;
  Og[(is * 32 + ti + 16) * 160 + js * 32 + tj] = a2;
  Og[(is * 32 + ti + 24) * 160 + js * 32 + tj] = a3;
}

// ---------------------------------------------------------------------------
// 3) Fold rotation into weights: W'[:,blk r] = W[:,blk r] @ (I + 2P_r)
// ---------------------------------------------------------------------------
__global__ __launch_bounds__(256) void fold_kernel(
    const float* __restrict__ Wq, const float* __restrict__ Wk,
    const float* __restrict__ Wv, const float* __restrict__ P,
    float* __restrict__ WqF, float* __restrict__ WkF,
    float* __restrict__ WvF) {
  int r = blockIdx.x;
  int rt = blockIdx.y;
  int w = blockIdx.z;
  int rows = (w == 0) ? H : CENC;
  if (rt * 64 >= rows) return;
  const float* Wg = (w == 0) ? Wq : ((w == 1) ? Wk : Wv);
  float* Og = (w == 0) ? WqF : ((w == 1) ? WkF : WvF);
  const float* Pg = P + (size_t)(w * RB + r) * BS * BS;
  __shared__ float As[64 * 160];
  __shared__ float Ps[160 * 32];
  for (int idx = threadIdx.x; idx < 64 * 160; idx += 256) {
    int rr = idx / 160, c = idx % 160;
    As[idx] = Wg[(size_t)(rt * 64 + rr) * H + r * 160 + c];
  }
  int ti = threadIdx.x / 32, tc = threadIdx.x % 32;
  for (int strip = 0; strip < 5; ++strip) {
    __syncthreads();
    for (int idx = threadIdx.x; idx < 160 * 32; idx += 256) {
      int d = idx / 32, cc = idx % 32;
      Ps[idx] = Pg[d * 160 + strip * 32 + cc];
    }
    __syncthreads();
    float acc[8];
#pragma unroll
    for (int m = 0; m < 8; m++) acc[m] = 0.f;
    for (int d = 0; d < 160; ++d) {
      float p = Ps[d * 32 + tc];
#pragma unroll
      for (int m = 0; m < 8; m++) acc[m] += As[(ti * 8 + m) * 160 + d] * p;
    }
#pragma unroll
    for (int m = 0; m < 8; m++) {
      int row = ti * 8 + m;
      Og[(size_t)(rt * 64 + row) * H + r * 160 + strip * 32 + tc] =
          As[row * 160 + strip * 32 + tc] + 2.f * acc[m];
    }
  }
}

// ---------------------------------------------------------------------------
// 4a) elementwise fp32 -> bf16 hi/lo split
// ---------------------------------------------------------------------------
__global__ __launch_bounds__(256) void split_kernel(
    const float* __restrict__ in, short* __restrict__ hi,
    short* __restrict__ lo, int n4) {
  int stride = gridDim.x * 256;
  for (int idx = blockIdx.x * 256 + threadIdx.x; idx < n4; idx += stride) {
    float4 v = ((const float4*)in)[idx];
    short h0 = f2bf(v.x), h1 = f2bf(v.y), h2 = f2bf(v.z), h3 = f2bf(v.w);
    short l0 = f2bf(v.x - bf2f(h0));
    short l1 = f2bf(v.y - bf2f(h1));
    short l2 = f2bf(v.z - bf2f(h2));
    short l3 = f2bf(v.w - bf2f(h3));
    ((short4*)hi)[idx] = make_short4(h0, h1, h2, h3);
    ((short4*)lo)[idx] = make_short4(l0, l1, l2, l3);
  }
}

// ---------------------------------------------------------------------------
// 4b) transpose + split: in [Kdim][Ndim] fp32 -> out [Ndim][Kdim] bf16 hi/lo
// ---------------------------------------------------------------------------
__global__ __launch_bounds__(256) void tsplit_kernel(
    const float* __restrict__ in, short* __restrict__ hi,
    short* __restrict__ lo, int Kdim, int Ndim) {
  __shared__ float tile[32][33];
  int kb = blockIdx.x * 32, nb = blockIdx.y * 32;
  int tx = threadIdx.x & 31, ty = threadIdx.x >> 5;
  for (int r = ty; r < 32; r += 8)
    tile[r][tx] = in[(size_t)(kb + r) * Ndim + nb + tx];
  __syncthreads();
  for (int r = ty; r < 32; r += 8) {
    float x = tile[tx][r];
    short h = f2bf(x);
    short l = f2bf(x - bf2f(h));
    size_t o = (size_t)(nb + r) * Kdim + kb + tx;
    hi[o] = h;
    lo[o] = l;
  }
}

// ---------------------------------------------------------------------------
// 5) split bf16 MFMA GEMM: C[M,N] = A[M,K] @ B[N,K]^T  (B stored transposed)
// ---------------------------------------------------------------------------
__global__ __launch_bounds__(256, 2) void gemm_mfma(
    const short* __restrict__ Ah, const short* __restrict__ Al,
    const short* __restrict__ Bh, const short* __restrict__ Bl,
    float* __restrict__ C, int M, int N, int K,
    const float* __restrict__ bias) {
  __shared__ __align__(16) short As[2][128][40];
  __shared__ __align__(16) short Bs[2][128][40];
  int t = threadIdx.x;
  int m0 = blockIdx.x * 128, n0 = blockIdx.y * 128;
  int wv = t >> 6, l = t & 63;
  int wm = (wv >> 1) * 64, wn = (wv & 1) * 64;
  f32x4 acc[4][4];
#pragma unroll
  for (int m = 0; m < 4; m++)
#pragma unroll
    for (int n = 0; n < 4; n++) acc[m][n] = (f32x4){0.f, 0.f, 0.f, 0.f};

  int lr = l & 15;
  int kq = (l >> 4) * 8;

  for (int k0 = 0; k0 < K; k0 += 32) {
    __syncthreads();
#pragma unroll
    for (int i = 0; i < 2; ++i) {
      int idx = t + i * 256;
      int row = idx >> 2, c = idx & 3;
      int ar = m0 + row;
      if (ar >= M) ar = M - 1;
      size_t ga = (size_t)ar * K + k0 + c * 8;
      size_t gb = (size_t)(n0 + row) * K + k0 + c * 8;
      *(short8v*)&As[0][row][c * 8] = *(const short8v*)&Ah[ga];
      *(short8v*)&As[1][row][c * 8] = *(const short8v*)&Al[ga];
      *(short8v*)&Bs[0][row][c * 8] = *(const short8v*)&Bh[gb];
      *(short8v*)&Bs[1][row][c * 8] = *(const short8v*)&Bl[gb];
    }
    __syncthreads();
    short8v ah[4], al[4], bh[4], bl[4];
#pragma unroll
    for (int m = 0; m < 4; ++m) {
      ah[m] = *(const short8v*)&As[0][wm + m * 16 + lr][kq];
      al[m] = *(const short8v*)&As[1][wm + m * 16 + lr][kq];
    }
#pragma unroll
    for (int n = 0; n < 4; ++n) {
      bh[n] = *(const short8v*)&Bs[0][wn + n * 16 + lr][kq];
      bl[n] = *(const short8v*)&Bs[1][wn + n * 16 + lr][kq];
    }
#pragma unroll
    for (int m = 0; m < 4; ++m)
#pragma unroll
      for (int n = 0; n < 4; ++n) {
        acc[m][n] = __builtin_amdgcn_mfma_f32_16x16x32_bf16(ah[m], bh[n],
                                                            acc[m][n], 0, 0, 0);
        acc[m][n] = __builtin_amdgcn_mfma_f32_16x16x32_bf16(ah[m], bl[n],
                                                            acc[m][n], 0, 0, 0);
        acc[m][n] = __builtin_amdgcn_mfma_f32_16x16x32_bf16(al[m], bh[n],
                                                            acc[m][n], 0, 0, 0);
      }
  }

  int rbase = m0 + wm + (l >> 4) * 4;
#pragma unroll
  for (int n = 0; n < 4; ++n) {
    int col = n0 + wn + n * 16 + lr;
    float bv = bias ? bias[col] : 0.f;
#pragma unroll
    for (int m = 0; m < 4; ++m) {
#pragma unroll
      for (int r = 0; r < 4; ++r) {
        int row = rbase + m * 16 + r;
        if (row < M) C[(size_t)row * N + col] = acc[m][n][r] + bv;
      }
    }
  }
}

// ---------------------------------------------------------------------------
// 6) Attention: one wg per (b, h, 256-query block); K/V staged once; register
//    softmax with 4-lane shuffle reduce; writes bf16 hi/lo output.
// ---------------------------------------------------------------------------
__global__ __launch_bounds__(256) void attn_kernel(
    const float* __restrict__ qbuf, const float* __restrict__ kbuf,
    const float* __restrict__ vbuf, short* __restrict__ aoh,
    short* __restrict__ aol) {
  int bid = blockIdx.x;              // grid = 16*20*4
  int qb = bid & 3;
  int h = (bid >> 2) % HEADS;
  int b = bid / (4 * HEADS);
  __shared__ float Ks[SE * 68];      // stride 68: conflict-free b128 reads
  __shared__ float Vs[80 * 64];      // padded rows 77..79 zeroed
  __shared__ float Ps[64 * 84];      // probs, stride 84
  int t = threadIdx.x;
  for (int idx = t; idx < 80 * 64; idx += 256) {
    int j = idx >> 6, d = idx & 63;
    float kv = 0.f, vv = 0.f;
    if (j < SE) {
      size_t g = (size_t)(b * SE + j) * H + h * 64 + d;
      kv = kbuf[g];
      vv = vbuf[g];
      Ks[j * 68 + d] = kv;
    }
    Vs[idx] = vv;
  }
  for (int idx = t; idx < 64 * 84; idx += 256) Ps[idx] = 0.f;
  __syncthreads();

  int qi = t >> 2, sl = t & 3;       // QK/softmax mapping
  int dPV = t & 63, qg = t >> 6;     // PV mapping

  for (int sub = 0; sub < 4; ++sub) {
    int qrow0 = b * SEQ + qb * 256 + sub * 64;
    const float* qp = qbuf + (size_t)(qrow0 + qi) * H + h * 64;
    float4 qr[16];
#pragma unroll
    for (int dd = 0; dd < 16; ++dd) qr[dd] = *(const float4*)&qp[dd * 4];

    float s[20];
    float m = -1e30f;
#pragma unroll
    for (int k = 0; k < 20; ++k) {
      int j = sl + 4 * k;
      float acc = -1e30f;
      if (j < SE) {
        acc = 0.f;
#pragma unroll
        for (int dd = 0; dd < 16; ++dd) {
          float4 k4 = *(const float4*)&Ks[j * 68 + dd * 4];
          acc += qr[dd].x * k4.x + qr[dd].y * k4.y + qr[dd].z * k4.z +
                 qr[dd].w * k4.w;
        }
        acc *= 0.125f;
      }
      s[k] = acc;
      m = fmaxf(m, acc);
    }
    m = fmaxf(m, __shfl_xor(m, 1));
    m = fmaxf(m, __shfl_xor(m, 2));
    float sum = 0.f;
#pragma unroll
    for (int k = 0; k < 20; ++k) {
      int j = sl + 4 * k;
      if (j < SE) {
        s[k] = __expf(s[k] - m);
        sum += s[k];
      }
    }
    sum += __shfl_xor(sum, 1);
    sum += __shfl_xor(sum, 2);
    float inv = 1.f / sum;
#pragma unroll
    for (int k = 0; k < 20; ++k) {
      int j = sl + 4 * k;
      if (j < SE) Ps[qi * 84 + j] = s[k] * inv;
    }
    __syncthreads();

    float acc[16];
#pragma unroll
    for (int mm = 0; mm < 16; mm++) acc[mm] = 0.f;
    for (int j4 = 0; j4 < 80; j4 += 4) {
      float v0 = Vs[(j4 + 0) * 64 + dPV];
      float v1 = Vs[(j4 + 1) * 64 + dPV];
      float v2 = Vs[(j4 + 2) * 64 + dPV];
      float v3 = Vs[(j4 + 3) * 64 + dPV];
#pragma unroll
      for (int mm = 0; mm < 16; mm++) {
        float4 p4 = *(const float4*)&Ps[(qg * 16 + mm) * 84 + j4];
        acc[mm] += p4.x * v0 + p4.y * v1 + p4.z * v2 + p4.w * v3;
      }
    }
#pragma unroll
    for (int mm = 0; mm < 16; mm++) {
      size_t o = (size_t)(qrow0 + qg * 16 + mm) * H + h * 64 + dPV;
      float v = acc[mm];
      short hh = f2bf(v);
      aoh[o] = hh;
      aol[o] = f2bf(v - bf2f(hh));
    }
    __syncthreads();
  }
}

// ---------------------------------------------------------------------------
extern "C" void kernel_launch(void* const* d_in, const int* in_sizes, int n_in,
                              void* d_out, int out_size, void* d_ws,
                              size_t ws_size, hipStream_t stream) {
  const float* hidden = (const float*)d_in[0];
  const float* enc = (const float*)d_in[1];
  const float* W_Q = (const float*)d_in[2];
  const float* W_K = (const float*)d_in[3];
  const float* W_V = (const float*)d_in[4];
  const float* Wq = (const float*)d_in[5];
  const float* Wk = (const float*)d_in[6];
  const float* Wv = (const float*)d_in[7];
  const float* Wo = (const float*)d_in[8];
  const float* bo = (const float*)d_in[9];
  float* out = (float*)d_out;
  float* ws = (float*)d_ws;

  float* Qs = ws + QS_OFF;
  float* Pa = ws + PA_OFF;
  float* Pb = ws + PB_OFF;
  float* WqF = ws + WQF_OFF;
  float* WkF = ws + WKF_OFF;
  float* WvF = ws + WVF_OFF;
  float* qbuf = ws + QBUF_OFF;
  float* kbuf = ws + KBUF_OFF;
  float* vbuf = ws + VBUF_OFF;
  short* HidH = (short*)(ws + HIDH_OFF);
  short* HidL = (short*)(ws + HIDL_OFF);
  short* EncH = (short*)(ws + ENCH_OFF);
  short* EncL = (short*)(ws + ENCL_OFF);
  short* WqTh = (short*)(ws + WQTH_OFF);
  short* WqTl = (short*)(ws + WQTL_OFF);
  short* WkTh = (short*)(ws + WKTH_OFF);
  short* WkTl = (short*)(ws + WKTL_OFF);
  short* WvTh = (short*)(ws + WVTH_OFF);
  short* WvTl = (short*)(ws + WVTL_OFF);
  short* WoTh = (short*)(ws + WOTH_OFF);
  short* WoTl = (short*)(ws + WOTL_OFF);
  short* AOh = HidH;  // overlay: hidden splits dead after q GEMM
  short* AOl = HidL;
  float* norms = Pa;  // overlay: Pa dead until first horner

  // Cayley via Neumann series folded into the projection weights
  zero_norms<<<1, 64, 0, stream>>>(norms);
  skew_norm_kernel<<<24, 256, 0, stream>>>(W_Q, W_K, W_V, norms);
  skew_scale_kernel<<<2400, 256, 0, stream>>>(W_Q, W_K, W_V, norms, Qs);
  horner_kernel<<<600, 256, 0, stream>>>(Qs, Qs, Pa);
  horner_kernel<<<600, 256, 0, stream>>>(Qs, Pa, Pb);
  horner_kernel<<<600, 256, 0, stream>>>(Qs, Pb, Pa);
  horner_kernel<<<600, 256, 0, stream>>>(Qs, Pa, Pb);
  horner_kernel<<<600, 256, 0, stream>>>(Qs, Pb, Pa);
  fold_kernel<<<dim3(8, 20, 3), 256, 0, stream>>>(Wq, Wk, Wv, Pa, WqF, WkF,
                                                  WvF);

  // weight transpose + bf16 hi/lo split
  tsplit_kernel<<<dim3(40, 40), 256, 0, stream>>>(WqF, WqTh, WqTl, H, H);
  tsplit_kernel<<<dim3(24, 40), 256, 0, stream>>>(WkF, WkTh, WkTl, CENC, H);
  tsplit_kernel<<<dim3(24, 40), 256, 0, stream>>>(WvF, WvTh, WvTl, CENC, H);
  tsplit_kernel<<<dim3(40, 40), 256, 0, stream>>>(Wo, WoTh, WoTl, H, H);

  // activation splits
  split_kernel<<<2048, 256, 0, stream>>>(hidden, HidH, HidL,
                                         (BATCH * SEQ * H) / 4);
  split_kernel<<<512, 256, 0, stream>>>(enc, EncH, EncL,
                                        (BATCH * SE * CENC) / 4);

  // projections (bf16x3 split MFMA)
  gemm_mfma<<<dim3(128, 10), 256, 0, stream>>>(HidH, HidL, WqTh, WqTl, qbuf,
                                               BATCH * SEQ, H, H, nullptr);
  gemm_mfma<<<dim3(10, 10), 256, 0, stream>>>(EncH, EncL, WkTh, WkTl, kbuf,
                                              BATCH * SE, H, CENC, nullptr);
  gemm_mfma<<<dim3(10, 10), 256, 0, stream>>>(EncH, EncL, WvTh, WvTl, vbuf,
                                              BATCH * SE, H, CENC, nullptr);

  // attention (writes bf16 hi/lo, overlaid on hidden-split buffers)
  attn_kernel<<<BATCH * HEADS * 4, 256, 0, stream>>>(qbuf, kbuf, vbuf, AOh,
                                                     AOl);

  // output projection + bias
  gemm_mfma<<<dim3(128, 10), 256, 0, stream>>>(AOh, AOl, WoTh, WoTl, out,
                                               BATCH * SEQ, H, H, bo);
}

// Round 5
// 1088.899 us; speedup vs baseline: 3.7767x; 3.7767x over previous
//
#include <hip/hip_runtime.h>
#include <cstddef>
#include <cstdint>

#define H 1280
#define RB 8
#define BS 160
#define HEADS 20
#define HD 64
#define BATCH 16
#define SEQ 1024
#define SE 77
#define CENC 768
#define CONSTR 1.28f
#define EPS_N 1e-8f

// workspace offsets (in floats)
#define QS_OFF    0u           // 614400
#define PA_OFF    614400u
#define PB_OFF    1228800u
#define WQF_OFF   1843200u     // 1638400
#define WKF_OFF   3481600u     // 983040
#define WVF_OFF   4464640u     // 983040
#define QBUF_OFF  5447680u     // 20971520
#define KBUF_OFF  26419200u    // 1576960
#define VBUF_OFF  27996160u    // 1576960
#define HIDH_OFF  29573120u    // 10485760 floats (20971520 shorts)
#define HIDL_OFF  40058880u    // 10485760
#define ENCH_OFF  50544640u    // 473088
#define ENCL_OFF  51017728u    // 473088
#define WQTH_OFF  51490816u    // 819200
#define WQTL_OFF  52310016u    // 819200
#define WKTH_OFF  53129216u    // 491520
#define WKTL_OFF  53620736u    // 491520
#define WVTH_OFF  54112256u    // 491520
#define WVTL_OFF  54603776u    // 491520
#define WOTH_OFF  55095296u    // 819200
#define WOTL_OFF  55914496u    // 819200
// AO (attn output, bf16 hi/lo) overlays HIDH/HIDL (dead after q GEMM)
// norms (3 floats) overlays PA (dead until first horner)

typedef __attribute__((ext_vector_type(8))) short short8v;
typedef __attribute__((ext_vector_type(4))) float f32x4;

__device__ __forceinline__ short f2bf(float x) {
  unsigned u = __float_as_uint(x);
  unsigned r = (u + 0x7fffu + ((u >> 16) & 1u)) >> 16;
  return (short)r;
}
__device__ __forceinline__ float bf2f(short h) {
  return __uint_as_float(((unsigned)(unsigned short)h) << 16);
}

// ---------------------------------------------------------------------------
// 1a) zero the 3-float norm accumulator
// ---------------------------------------------------------------------------
__global__ void zero_norms(float* __restrict__ norms) {
  if (threadIdx.x < 3) norms[threadIdx.x] = 0.f;
}

// 1b) partial Frobenius norms of Q = W - W^T. grid = 24 (w*8+r), 256 thr.
__global__ __launch_bounds__(256) void skew_norm_kernel(
    const float* __restrict__ W0, const float* __restrict__ W1,
    const float* __restrict__ W2, float* __restrict__ norms) {
  int wr = blockIdx.x;
  int w = wr >> 3, r = wr & 7;
  const float* Wb =
      ((w == 0) ? W0 : ((w == 1) ? W1 : W2)) + (size_t)r * BS * BS;
  float local = 0.f;
  for (int idx = threadIdx.x; idx < BS * BS; idx += 256) {
    int i = idx / BS, j = idx % BS;
    float q = Wb[idx] - Wb[j * BS + i];
    local += q * q;
  }
#pragma unroll
  for (int off = 32; off > 0; off >>= 1) local += __shfl_down(local, off);
  __shared__ float wsum[4];
  if ((threadIdx.x & 63) == 0) wsum[threadIdx.x >> 6] = local;
  __syncthreads();
  if (threadIdx.x == 0)
    atomicAdd(&norms[w], wsum[0] + wsum[1] + wsum[2] + wsum[3]);
}

// 1c) scale pass: Qs = (W - W^T) * (min(n,c)+eps)/(n+eps). grid 2400, 256 thr.
__global__ __launch_bounds__(256) void skew_scale_kernel(
    const float* __restrict__ W0, const float* __restrict__ W1,
    const float* __restrict__ W2, const float* __restrict__ norms,
    float* __restrict__ Qs) {
  int idx = blockIdx.x * 256 + threadIdx.x;  // < 614400
  int w = idx / (RB * BS * BS);
  int rem = idx - w * (RB * BS * BS);
  int r = rem / (BS * BS);
  int ij = rem - r * (BS * BS);
  int i = ij / BS, j = ij - i * BS;
  const float* Wb =
      ((w == 0) ? W0 : ((w == 1) ? W1 : W2)) + (size_t)r * BS * BS;
  float n = sqrtf(norms[w]);
  float sc = (fminf(n, CONSTR) + EPS_N) / (n + EPS_N);
  Qs[idx] = (Wb[ij] - Wb[j * BS + i]) * sc;
}

// ---------------------------------------------------------------------------
// 2) Horner step: Pout = Q @ (Pin + I) per 160x160 block.
// ---------------------------------------------------------------------------
__global__ __launch_bounds__(256) void horner_kernel(
    const float* __restrict__ Qs, const float* __restrict__ Pin,
    float* __restrict__ Pout) {
  int wr = blockIdx.x / 25;
  int st = blockIdx.x % 25;
  int is = st / 5, js = st % 5;
  const float* Ag = Qs + (size_t)wr * BS * BS;
  const float* Bg = Pin + (size_t)wr * BS * BS;
  float* Og = Pout + (size_t)wr * BS * BS;
  __shared__ float As[32 * 160];
  __shared__ float Bsh[160 * 32];
  for (int idx = threadIdx.x; idx < 32 * 160; idx += 256) {
    int rr = idx / 160, c = idx % 160;
    As[idx] = Ag[(is * 32 + rr) * 160 + c];
    int k = idx / 32, jj = idx % 32;
    int jglob = js * 32 + jj;
    float v = Bg[k * 160 + jglob];
    if (k == jglob) v += 1.f;
    Bsh[k * 32 + jj] = v;
  }
  __syncthreads();
  int ti = threadIdx.x / 32, tj = threadIdx.x % 32;
  float a0 = 0.f, a1 = 0.f, a2 = 0.f, a3 = 0.f;
  for (int k = 0; k < 160; ++k) {
    float b = Bsh[k * 32 + tj];
    a0 += As[(ti)*160 + k] * b;
    a1 += As[(ti + 8) * 160 + k] * b;
    a2 += As[(ti + 16) * 160 + k] * b;
    a3 += As[(ti + 24) * 160 + k] * b;
  }
  Og[(is * 32 + ti) * 160 + js * 32 + tj] = a0;
  Og[(is * 32 + ti + 8) * 160 + js * 32 + tj] = a1;
  Og[(is * 32 + ti + 16) * 160 + js * 32 + tj] = a2;
  Og[(is * 32 + ti + 24) * 160 + js * 32 + tj] = a3;
}

// ---------------------------------------------------------------------------
// 3) Fold rotation into weights: W'[:,blk r] = W[:,blk r] @ (I + 2P_r)
// ---------------------------------------------------------------------------
__global__ __launch_bounds__(256) void fold_kernel(
    const float* __restrict__ Wq, const float* __restrict__ Wk,
    const float* __restrict__ Wv, const float* __restrict__ P,
    float* __restrict__ WqF, float* __restrict__ WkF,
    float* __restrict__ WvF) {
  int r = blockIdx.x;
  int rt = blockIdx.y;
  int w = blockIdx.z;
  int rows = (w == 0) ? H : CENC;
  if (rt * 64 >= rows) return;
  const float* Wg = (w == 0) ? Wq : ((w == 1) ? Wk : Wv);
  float* Og = (w == 0) ? WqF : ((w == 1) ? WkF : WvF);
  const float* Pg = P + (size_t)(w * RB + r) * BS * BS;
  __shared__ float As[64 * 160];
  __shared__ float Ps[160 * 32];
  for (int idx = threadIdx.x; idx < 64 * 160; idx += 256) {
    int rr = idx / 160, c = idx % 160;
    As[idx] = Wg[(size_t)(rt * 64 + rr) * H + r * 160 + c];
  }
  int ti = threadIdx.x / 32, tc = threadIdx.x % 32;
  for (int strip = 0; strip < 5; ++strip) {
    __syncthreads();
    for (int idx = threadIdx.x; idx < 160 * 32; idx += 256) {
      int d = idx / 32, cc = idx % 32;
      Ps[idx] = Pg[d * 160 + strip * 32 + cc];
    }
    __syncthreads();
    float acc[8];
#pragma unroll
    for (int m = 0; m < 8; m++) acc[m] = 0.f;
    for (int d = 0; d < 160; ++d) {
      float p = Ps[d * 32 + tc];
#pragma unroll
      for (int m = 0; m < 8; m++) acc[m] += As[(ti * 8 + m) * 160 + d] * p;
    }
#pragma unroll
    for (int m = 0; m < 8; m++) {
      int row = ti * 8 + m;
      Og[(size_t)(rt * 64 + row) * H + r * 160 + strip * 32 + tc] =
          As[row * 160 + strip * 32 + tc] + 2.f * acc[m];
    }
  }
}

// ---------------------------------------------------------------------------
// 4a) elementwise fp32 -> bf16 hi/lo split
// ---------------------------------------------------------------------------
__global__ __launch_bounds__(256) void split_kernel(
    const float* __restrict__ in, short* __restrict__ hi,
    short* __restrict__ lo, int n4) {
  int stride = gridDim.x * 256;
  for (int idx = blockIdx.x * 256 + threadIdx.x; idx < n4; idx += stride) {
    float4 v = ((const float4*)in)[idx];
    short h0 = f2bf(v.x), h1 = f2bf(v.y), h2 = f2bf(v.z), h3 = f2bf(v.w);
    short l0 = f2bf(v.x - bf2f(h0));
    short l1 = f2bf(v.y - bf2f(h1));
    short l2 = f2bf(v.z - bf2f(h2));
    short l3 = f2bf(v.w - bf2f(h3));
    ((short4*)hi)[idx] = make_short4(h0, h1, h2, h3);
    ((short4*)lo)[idx] = make_short4(l0, l1, l2, l3);
  }
}

// ---------------------------------------------------------------------------
// 4b) transpose + split: in [Kdim][Ndim] fp32 -> out [Ndim][Kdim] bf16 hi/lo
// ---------------------------------------------------------------------------
__global__ __launch_bounds__(256) void tsplit_kernel(
    const float* __restrict__ in, short* __restrict__ hi,
    short* __restrict__ lo, int Kdim, int Ndim) {
  __shared__ float tile[32][33];
  int kb = blockIdx.x * 32, nb = blockIdx.y * 32;
  int tx = threadIdx.x & 31, ty = threadIdx.x >> 5;
  for (int r = ty; r < 32; r += 8)
    tile[r][tx] = in[(size_t)(kb + r) * Ndim + nb + tx];
  __syncthreads();
  for (int r = ty; r < 32; r += 8) {
    float x = tile[tx][r];
    short h = f2bf(x);
    short l = f2bf(x - bf2f(h));
    size_t o = (size_t)(nb + r) * Kdim + kb + tx;
    hi[o] = h;
    lo[o] = l;
  }
}

// ---------------------------------------------------------------------------
// 5) split bf16 MFMA GEMM: C[M,N] = A[M,K] @ B[N,K]^T  (B stored transposed)
// ---------------------------------------------------------------------------
__global__ __launch_bounds__(256, 2) void gemm_mfma(
    const short* __restrict__ Ah, const short* __restrict__ Al,
    const short* __restrict__ Bh, const short* __restrict__ Bl,
    float* __restrict__ C, int M, int N, int K,
    const float* __restrict__ bias) {
  __shared__ __align__(16) short As[2][128][40];
  __shared__ __align__(16) short Bs[2][128][40];
  int t = threadIdx.x;
  int m0 = blockIdx.x * 128, n0 = blockIdx.y * 128;
  int wv = t >> 6, l = t & 63;
  int wm = (wv >> 1) * 64, wn = (wv & 1) * 64;
  f32x4 acc[4][4];
#pragma unroll
  for (int m = 0; m < 4; m++)
#pragma unroll
    for (int n = 0; n < 4; n++) acc[m][n] = (f32x4){0.f, 0.f, 0.f, 0.f};

  int lr = l & 15;
  int kq = (l >> 4) * 8;

  for (int k0 = 0; k0 < K; k0 += 32) {
    __syncthreads();
#pragma unroll
    for (int i = 0; i < 2; ++i) {
      int idx = t + i * 256;
      int row = idx >> 2, c = idx & 3;
      int ar = m0 + row;
      if (ar >= M) ar = M - 1;
      size_t ga = (size_t)ar * K + k0 + c * 8;
      size_t gb = (size_t)(n0 + row) * K + k0 + c * 8;
      *(short8v*)&As[0][row][c * 8] = *(const short8v*)&Ah[ga];
      *(short8v*)&As[1][row][c * 8] = *(const short8v*)&Al[ga];
      *(short8v*)&Bs[0][row][c * 8] = *(const short8v*)&Bh[gb];
      *(short8v*)&Bs[1][row][c * 8] = *(const short8v*)&Bl[gb];
    }
    __syncthreads();
    short8v ah[4], al[4], bh[4], bl[4];
#pragma unroll
    for (int m = 0; m < 4; ++m) {
      ah[m] = *(const short8v*)&As[0][wm + m * 16 + lr][kq];
      al[m] = *(const short8v*)&As[1][wm + m * 16 + lr][kq];
    }
#pragma unroll
    for (int n = 0; n < 4; ++n) {
      bh[n] = *(const short8v*)&Bs[0][wn + n * 16 + lr][kq];
      bl[n] = *(const short8v*)&Bs[1][wn + n * 16 + lr][kq];
    }
#pragma unroll
    for (int m = 0; m < 4; ++m)
#pragma unroll
      for (int n = 0; n < 4; ++n) {
        acc[m][n] = __builtin_amdgcn_mfma_f32_16x16x32_bf16(ah[m], bh[n],
                                                            acc[m][n], 0, 0, 0);
        acc[m][n] = __builtin_amdgcn_mfma_f32_16x16x32_bf16(ah[m], bl[n],
                                                            acc[m][n], 0, 0, 0);
        acc[m][n] = __builtin_amdgcn_mfma_f32_16x16x32_bf16(al[m], bh[n],
                                                            acc[m][n], 0, 0, 0);
      }
  }

  int rbase = m0 + wm + (l >> 4) * 4;
#pragma unroll
  for (int n = 0; n < 4; ++n) {
    int col = n0 + wn + n * 16 + lr;
    float bv = bias ? bias[col] : 0.f;
#pragma unroll
    for (int m = 0; m < 4; ++m) {
#pragma unroll
      for (int r = 0; r < 4; ++r) {
        int row = rbase + m * 16 + r;
        if (row < M) C[(size_t)row * N + col] = acc[m][n][r] + bv;
      }
    }
  }
}

// ---------------------------------------------------------------------------
// 6) Attention: one wg per (b, h, 256-query block); K/V staged once.
//    Thread (qi, sl) owns q-row qi's 16-dim slice d0=sl*16. QK uses a 3-shfl
//    distribute-reduce over the 4-lane group; probs stay in registers; PV via
//    __shfl broadcast. Low register footprint, no Ps LDS, no inner barriers.
// ---------------------------------------------------------------------------
__global__ __launch_bounds__(256) void attn_kernel(
    const float* __restrict__ qbuf, const float* __restrict__ kbuf,
    const float* __restrict__ vbuf, short* __restrict__ aoh,
    short* __restrict__ aol) {
  int bid = blockIdx.x;  // grid = 16*20*4
  int qb = bid & 3;
  int h = (bid >> 2) % HEADS;
  int b = bid / (4 * HEADS);
  __shared__ float Ks[SE * 68];  // stride 68
  __shared__ float Vs[SE * 64];
  int t = threadIdx.x;
  for (int idx = t; idx < SE * 16; idx += 256) {
    int j = idx >> 4, dq = idx & 15;
    size_t g = (size_t)(b * SE + j) * H + h * 64 + dq * 4;
    *(float4*)&Ks[j * 68 + dq * 4] = *(const float4*)&kbuf[g];
    *(float4*)&Vs[j * 64 + dq * 4] = *(const float4*)&vbuf[g];
  }
  __syncthreads();

  int qi = t >> 2, sl = t & 3;
  int d0 = sl * 16;
  bool b0 = (sl & 1) != 0, b1 = (sl & 2) != 0;

  for (int sub = 0; sub < 4; ++sub) {
    int qrow0 = b * SEQ + qb * 256 + sub * 64;
    const float* qp = qbuf + (size_t)(qrow0 + qi) * H + h * 64 + d0;
    float4 q0 = *(const float4*)&qp[0];
    float4 q1 = *(const float4*)&qp[4];
    float4 q2 = *(const float4*)&qp[8];
    float4 q3 = *(const float4*)&qp[12];

    float s[20];
#pragma unroll
    for (int k = 0; k < 20; ++k) {
      float p[4];
#pragma unroll
      for (int jj = 0; jj < 4; ++jj) {
        int j = 4 * k + jj;
        if (j < SE) {
          const float* kp = &Ks[j * 68 + d0];
          float4 k0 = *(const float4*)&kp[0];
          float4 k1 = *(const float4*)&kp[4];
          float4 k2 = *(const float4*)&kp[8];
          float4 k3 = *(const float4*)&kp[12];
          p[jj] = q0.x * k0.x + q0.y * k0.y + q0.z * k0.z + q0.w * k0.w +
                  q1.x * k1.x + q1.y * k1.y + q1.z * k1.z + q1.w * k1.w +
                  q2.x * k2.x + q2.y * k2.y + q2.z * k2.z + q2.w * k2.w +
                  q3.x * k3.x + q3.y * k3.y + q3.z * k3.z + q3.w * k3.w;
        } else {
          p[jj] = 0.f;
        }
      }
      // distribute-reduce: lane sl ends with full dot for j = 4k+sl
      float sa = b0 ? p[0] : p[1];
      float sb = b0 ? p[2] : p[3];
      float ra = __shfl_xor(sa, 1);
      float rb = __shfl_xor(sb, 1);
      float ka = (b0 ? p[1] : p[0]) + ra;
      float kb = (b0 ? p[3] : p[2]) + rb;
      float sc_ = b1 ? ka : kb;
      float rc = __shfl_xor(sc_, 2);
      s[k] = ((b1 ? kb : ka) + rc) * 0.125f;
    }
    // lanes sl>0 at k=19 correspond to j=77..79: invalid
    if (sl != 0) s[19] = -1e30f;

    float m = -1e30f;
#pragma unroll
    for (int k = 0; k < 20; ++k) m = fmaxf(m, s[k]);
    m = fmaxf(m, __shfl_xor(m, 1));
    m = fmaxf(m, __shfl_xor(m, 2));
    float sum = 0.f;
#pragma unroll
    for (int k = 0; k < 20; ++k) {
      s[k] = __expf(s[k] - m);
      sum += s[k];
    }
    sum += __shfl_xor(sum, 1);
    sum += __shfl_xor(sum, 2);
    float inv = 1.f / sum;

    float4 a0 = {0.f, 0.f, 0.f, 0.f}, a1 = {0.f, 0.f, 0.f, 0.f};
    float4 a2 = {0.f, 0.f, 0.f, 0.f}, a3 = {0.f, 0.f, 0.f, 0.f};
#pragma unroll
    for (int k = 0; k < 20; ++k) {
#pragma unroll
      for (int src = 0; src < 4; ++src) {
        int j = 4 * k + src;
        if (j < SE) {
          float p = __shfl(s[k], src, 4);
          const float* vp = &Vs[j * 64 + d0];
          float4 v0 = *(const float4*)&vp[0];
          float4 v1 = *(const float4*)&vp[4];
          float4 v2 = *(const float4*)&vp[8];
          float4 v3 = *(const float4*)&vp[12];
          a0.x += p * v0.x; a0.y += p * v0.y; a0.z += p * v0.z; a0.w += p * v0.w;
          a1.x += p * v1.x; a1.y += p * v1.y; a1.z += p * v1.z; a1.w += p * v1.w;
          a2.x += p * v2.x; a2.y += p * v2.y; a2.z += p * v2.z; a2.w += p * v2.w;
          a3.x += p * v3.x; a3.y += p * v3.y; a3.z += p * v3.z; a3.w += p * v3.w;
        }
      }
    }

    size_t o = (size_t)(qrow0 + qi) * H + h * 64 + d0;
    float of[16] = {a0.x * inv, a0.y * inv, a0.z * inv, a0.w * inv,
                    a1.x * inv, a1.y * inv, a1.z * inv, a1.w * inv,
                    a2.x * inv, a2.y * inv, a2.z * inv, a2.w * inv,
                    a3.x * inv, a3.y * inv, a3.z * inv, a3.w * inv};
    short8v hv0, hv1, lv0, lv1;
#pragma unroll
    for (int i = 0; i < 8; ++i) {
      short hh = f2bf(of[i]);
      hv0[i] = hh;
      lv0[i] = f2bf(of[i] - bf2f(hh));
    }
#pragma unroll
    for (int i = 0; i < 8; ++i) {
      short hh = f2bf(of[8 + i]);
      hv1[i] = hh;
      lv1[i] = f2bf(of[8 + i] - bf2f(hh));
    }
    *(short8v*)&aoh[o] = hv0;
    *(short8v*)&aoh[o + 8] = hv1;
    *(short8v*)&aol[o] = lv0;
    *(short8v*)&aol[o + 8] = lv1;
  }
}

// ---------------------------------------------------------------------------
extern "C" void kernel_launch(void* const* d_in, const int* in_sizes, int n_in,
                              void* d_out, int out_size, void* d_ws,
                              size_t ws_size, hipStream_t stream) {
  const float* hidden = (const float*)d_in[0];
  const float* enc = (const float*)d_in[1];
  const float* W_Q = (const float*)d_in[2];
  const float* W_K = (const float*)d_in[3];
  const float* W_V = (const float*)d_in[4];
  const float* Wq = (const float*)d_in[5];
  const float* Wk = (const float*)d_in[6];
  const float* Wv = (const float*)d_in[7];
  const float* Wo = (const float*)d_in[8];
  const float* bo = (const float*)d_in[9];
  float* out = (float*)d_out;
  float* ws = (float*)d_ws;

  float* Qs = ws + QS_OFF;
  float* Pa = ws + PA_OFF;
  float* Pb = ws + PB_OFF;
  float* WqF = ws + WQF_OFF;
  float* WkF = ws + WKF_OFF;
  float* WvF = ws + WVF_OFF;
  float* qbuf = ws + QBUF_OFF;
  float* kbuf = ws + KBUF_OFF;
  float* vbuf = ws + VBUF_OFF;
  short* HidH = (short*)(ws + HIDH_OFF);
  short* HidL = (short*)(ws + HIDL_OFF);
  short* EncH = (short*)(ws + ENCH_OFF);
  short* EncL = (short*)(ws + ENCL_OFF);
  short* WqTh = (short*)(ws + WQTH_OFF);
  short* WqTl = (short*)(ws + WQTL_OFF);
  short* WkTh = (short*)(ws + WKTH_OFF);
  short* WkTl = (short*)(ws + WKTL_OFF);
  short* WvTh = (short*)(ws + WVTH_OFF);
  short* WvTl = (short*)(ws + WVTL_OFF);
  short* WoTh = (short*)(ws + WOTH_OFF);
  short* WoTl = (short*)(ws + WOTL_OFF);
  short* AOh = HidH;  // overlay: hidden splits dead after q GEMM
  short* AOl = HidL;
  float* norms = Pa;  // overlay: Pa dead until first horner

  // Cayley via Neumann series folded into the projection weights
  zero_norms<<<1, 64, 0, stream>>>(norms);
  skew_norm_kernel<<<24, 256, 0, stream>>>(W_Q, W_K, W_V, norms);
  skew_scale_kernel<<<2400, 256, 0, stream>>>(W_Q, W_K, W_V, norms, Qs);
  horner_kernel<<<600, 256, 0, stream>>>(Qs, Qs, Pa);
  horner_kernel<<<600, 256, 0, stream>>>(Qs, Pa, Pb);
  horner_kernel<<<600, 256, 0, stream>>>(Qs, Pb, Pa);
  horner_kernel<<<600, 256, 0, stream>>>(Qs, Pa, Pb);
  horner_kernel<<<600, 256, 0, stream>>>(Qs, Pb, Pa);
  fold_kernel<<<dim3(8, 20, 3), 256, 0, stream>>>(Wq, Wk, Wv, Pa, WqF, WkF,
                                                  WvF);

  // weight transpose + bf16 hi/lo split
  tsplit_kernel<<<dim3(40, 40), 256, 0, stream>>>(WqF, WqTh, WqTl, H, H);
  tsplit_kernel<<<dim3(24, 40), 256, 0, stream>>>(WkF, WkTh, WkTl, CENC, H);
  tsplit_kernel<<<dim3(24, 40), 256, 0, stream>>>(WvF, WvTh, WvTl, CENC, H);
  tsplit_kernel<<<dim3(40, 40), 256, 0, stream>>>(Wo, WoTh, WoTl, H, H);

  // activation splits
  split_kernel<<<2048, 256, 0, stream>>>(hidden, HidH, HidL,
                                         (BATCH * SEQ * H) / 4);
  split_kernel<<<512, 256, 0, stream>>>(enc, EncH, EncL,
                                        (BATCH * SE * CENC) / 4);

  // projections (bf16x3 split MFMA)
  gemm_mfma<<<dim3(128, 10), 256, 0, stream>>>(HidH, HidL, WqTh, WqTl, qbuf,
                                               BATCH * SEQ, H, H, nullptr);
  gemm_mfma<<<dim3(10, 10), 256, 0, stream>>>(EncH, EncL, WkTh, WkTl, kbuf,
                                              BATCH * SE, H, CENC, nullptr);
  gemm_mfma<<<dim3(10, 10), 256, 0, stream>>>(EncH, EncL, WvTh, WvTl, vbuf,
                                              BATCH * SE, H, CENC, nullptr);

  // attention (writes bf16 hi/lo, overlaid on hidden-split buffers)
  attn_kernel<<<BATCH * HEADS * 4, 256, 0, stream>>>(qbuf, kbuf, vbuf, AOh,
                                                     AOl);

  // output projection + bias
  gemm_mfma<<<dim3(128, 10), 256, 0, stream>>>(AOh, AOl, WoTh, WoTl, out,
                                               BATCH * SEQ, H, H, bo);
}